// Round 4
// baseline (1044.606 us; speedup 1.0000x reference)
//
#include <hip/hip_runtime.h>
#include <hip/hip_bf16.h>
#include <cmath>

typedef unsigned short u16;
typedef __attribute__((ext_vector_type(8))) short bf16x8;
typedef __attribute__((ext_vector_type(4))) float f32x4;

#define B_    2
#define S_    2048
#define H_    4096
#define NH_   32
#define NKV_  8
#define HD_   128
#define WIN_  1024

__device__ __forceinline__ u16 f2b(float f) {
  union { float f; unsigned u; } v; v.f = f;
  unsigned r = v.u + 0x7fffu + ((v.u >> 16) & 1u);
  return (u16)(r >> 16);
}
__device__ __forceinline__ float b2f(u16 h) {
  union { unsigned u; float f; } v; v.u = ((unsigned)h) << 16;
  return v.f;
}

__device__ __forceinline__ void storeC(float* p, float v) { *p = v; }
__device__ __forceinline__ void storeC(u16* p, float v)   { *p = f2b(v); }

// async global->LDS, 16B per lane; LDS dest must be wave-base + lane*16
__device__ __forceinline__ void gl2lds(const u16* g, u16* l) {
  __builtin_amdgcn_global_load_lds(
      (const __attribute__((address_space(1))) unsigned int*)(g),
      (__attribute__((address_space(3))) unsigned int*)(l), 16, 0, 0);
}

// ---------------- fp32 -> bf16 conversion ----------------
__global__ __launch_bounds__(256) void cvt_bf16(const float* __restrict__ s,
                                                u16* __restrict__ d, int n4) {
  int i = blockIdx.x * 256 + threadIdx.x;
  if (i < n4) {
    float4 v = ((const float4*)s)[i];
    ushort4 o;
    o.x = f2b(v.x); o.y = f2b(v.y); o.z = f2b(v.z); o.w = f2b(v.w);
    ((ushort4*)d)[i] = o;
  }
}

// ---- GEMM: C[M,N] = A[M,K] * W[N,K]^T, bf16 in, m97-style async staging ----
// BM x 128 tile, BK=32, 4 waves (2x2). VT=1: write output transposed as
// Vt[(b*8+hk)*128+d][s] (for the V projection), C must be u16*.
template <int BM, int VT, typename OutT>
__global__ __launch_bounds__(256) void gemm_bt(const u16* __restrict__ A,
                                               const u16* __restrict__ W,
                                               OutT* __restrict__ C,
                                               int M, int N, int K) {
  __shared__ u16 As[BM * 32];
  __shared__ u16 Bs[128 * 32];
  const int t = threadIdx.x;
  const int lane = t & 63, wave = t >> 6;
  const int quad = lane >> 4, l16 = lane & 15;
  const int wm = wave >> 1, wn = wave & 1;
  constexpr int WM = BM / 2;
  constexpr int MI = WM / 16;
  const size_t m0 = (size_t)blockIdx.y * BM, n0 = (size_t)blockIdx.x * 128;

  f32x4 acc[MI][4] = {};
  const int srow = lane >> 2, skc = lane & 3;

  for (int k0 = 0; k0 < K; k0 += 32) {
    __syncthreads();
#pragma unroll
    for (int i = 0; i < BM / 64; i++) {
      int row = wave * (BM / 4) + i * 16 + srow;
      gl2lds(A + (m0 + row) * K + k0 + skc * 8, &As[row * 32 + skc * 8]);
    }
#pragma unroll
    for (int i = 0; i < 2; i++) {
      int row = wave * 32 + i * 16 + srow;
      gl2lds(W + (n0 + row) * K + k0 + skc * 8, &Bs[row * 32 + skc * 8]);
    }
    __syncthreads();
    bf16x8 af[MI], bfr[4];
#pragma unroll
    for (int i = 0; i < MI; i++)
      af[i] = *(const bf16x8*)(&As[(wm * WM + i * 16 + l16) * 32 + quad * 8]);
#pragma unroll
    for (int i = 0; i < 4; i++)
      bfr[i] = *(const bf16x8*)(&Bs[(wn * 64 + i * 16 + l16) * 32 + quad * 8]);
#pragma unroll
    for (int mi = 0; mi < MI; mi++)
#pragma unroll
      for (int nj = 0; nj < 4; nj++)
        acc[mi][nj] = __builtin_amdgcn_mfma_f32_16x16x32_bf16(
            af[mi], bfr[nj], acc[mi][nj], 0, 0, 0);
  }

#pragma unroll
  for (int mi = 0; mi < MI; mi++) {
    size_t rbase = m0 + wm * WM + mi * 16 + quad * 4;
#pragma unroll
    for (int nj = 0; nj < 4; nj++) {
      int col = (int)n0 + wn * 64 + nj * 16 + l16;
      if (VT) {
        // V^T output: Vt[((b*8+hk)*128+d)*2048 + s], 4 consecutive s per lane
        int hk = col >> 7, d = col & 127;
        int bb = (int)(rbase >> 11), ss = (int)(rbase & 2047);
        u16 tmp[4];
#pragma unroll
        for (int e = 0; e < 4; e++) tmp[e] = f2b(acc[mi][nj][e]);
        *(uint2*)((u16*)C + (((size_t)(bb * 8 + hk) * 128 + d) * 2048 + ss)) =
            *(uint2*)tmp;
      } else {
#pragma unroll
        for (int e = 0; e < 4; e++)
          storeC(&C[(rbase + e) * N + col], acc[mi][nj][e]);
      }
    }
  }
}

// ------- RoPE in-place on bf16 [B*S, nh, 128], folds `sc` into output -------
__global__ __launch_bounds__(256) void rope_k(u16* __restrict__ X,
                                              const int* __restrict__ pos,
                                              int log2nh, float sc) {
  int idx = blockIdx.x * 256 + threadIdx.x;
  int i = idx & 63;
  int bsh = idx >> 6;
  int h = bsh & ((1 << log2nh) - 1);
  int bs = bsh >> log2nh;
  int p = pos[bs];
  float inv = exp2f(-(float)i * (13.287712379549449f / 64.0f));
  float ang = (float)p * inv;
  float sn, c;
  sincosf(ang, &sn, &c);
  size_t base = ((((size_t)bs) << log2nh) + h) * HD_;
  float x1 = b2f(X[base + i]), x2 = b2f(X[base + i + 64]);
  X[base + i]      = f2b((x1 * c - x2 * sn) * sc);
  X[base + i + 64] = f2b((x2 * c + x1 * sn) * sc);
}

// ---------------- flash attention, sliding window, 64-key tiles -------------
// grid (S/64, NH, B), 256 threads; wave w handles 16 q rows.
__global__ __launch_bounds__(256) void attn_k(const u16* __restrict__ Q,
                                              const u16* __restrict__ K,
                                              const u16* __restrict__ Vt,
                                              u16* __restrict__ O) {
  __shared__ u16 Ks[64 * 136];     // [key][d], pad 8
  __shared__ u16 Vs[128 * 72];     // [d][key], pad 8
  __shared__ u16 Ps[4][16 * 72];   // per-wave P scratch [q][key], pad 8

  const int t = threadIdx.x, wave = t >> 6, lane = t & 63;
  const int quad = lane >> 4, l16 = lane & 15;
  const int q0 = blockIdx.x * 64, h = blockIdx.y, b = blockIdx.z;
  const int hk = h >> 2;
  const int qw = q0 + wave * 16;

  bf16x8 qf[4];  // Q pre-scaled by 1/sqrt(128) in rope
  {
    size_t qrow = (((size_t)(b * S_ + qw + l16)) * NH_ + h) * HD_;
#pragma unroll
    for (int kk = 0; kk < 4; kk++)
      qf[kk] = *(const bf16x8*)(Q + qrow + kk * 32 + quad * 8);
  }

  f32x4 o_acc[8] = {};
  float m_i[4], l_i[4];
#pragma unroll
  for (int e = 0; e < 4; e++) { m_i[e] = -1e30f; l_i[e] = 0.0f; }

  int lo = q0 - (WIN_ - 1); if (lo < 0) lo = 0;
  const int lo_t = lo & ~63;
  const size_t vbase = ((size_t)(b * NKV_ + hk)) * HD_ * S_;

  for (int kt = lo_t; kt <= q0 + 63; kt += 64) {
    __syncthreads();
    // stage K tile [64 keys][128 d]
#pragma unroll
    for (int i = 0; i < 4; i++) {
      int c = t + 256 * i;
      int row = c >> 4, dc = c & 15;
      int krow = min(kt + row, S_ - 1);
      uint4 v = *(const uint4*)(K + (((size_t)(b * S_ + krow)) * NKV_ + hk) * HD_ + dc * 8);
      *(uint4*)(&Ks[row * 136 + dc * 8]) = v;
    }
    // stage V^T tile [128 d][64 keys]
#pragma unroll
    for (int i = 0; i < 4; i++) {
      int c = t + 256 * i;
      int d = c >> 3, kc = c & 7;
      int kcc = min(kt + kc * 8, S_ - 8);
      uint4 v = *(const uint4*)(Vt + vbase + (size_t)d * S_ + kcc);
      *(uint4*)(&Vs[d * 72 + kc * 8]) = v;
    }
    __syncthreads();

    if (kt <= qw + 15 && kt + 63 >= qw - (WIN_ - 1)) {
      f32x4 s[4] = {};
#pragma unroll
      for (int kk = 0; kk < 4; kk++) {
#pragma unroll
        for (int c = 0; c < 4; c++) {
          bf16x8 bK = *(const bf16x8*)(&Ks[(c * 16 + l16) * 136 + kk * 32 + quad * 8]);
          s[c] = __builtin_amdgcn_mfma_f32_16x16x32_bf16(qf[kk], bK, s[c], 0, 0, 0);
        }
      }
      const bool full = (kt + 63 <= qw) && (kt >= qw + 16 - WIN_);
      if (!full) {
#pragma unroll
        for (int c = 0; c < 4; c++)
#pragma unroll
          for (int e = 0; e < 4; e++) {
            int qi = qw + quad * 4 + e;
            int ki = kt + c * 16 + l16;
            bool a = (ki <= qi) && (qi - ki < WIN_);
            s[c][e] = a ? s[c][e] : -1e30f;
          }
      }
      u16* P = &Ps[wave][0];
#pragma unroll
      for (int e = 0; e < 4; e++) {
        float mx = fmaxf(fmaxf(s[0][e], s[1][e]), fmaxf(s[2][e], s[3][e]));
#pragma unroll
        for (int off = 1; off < 16; off <<= 1)
          mx = fmaxf(mx, __shfl_xor(mx, off, 64));
        float mn = fmaxf(m_i[e], mx);
        float al = __expf(m_i[e] - mn);
        m_i[e] = mn;
        float p0 = __expf(s[0][e] - mn);
        float p1 = __expf(s[1][e] - mn);
        float p2 = __expf(s[2][e] - mn);
        float p3 = __expf(s[3][e] - mn);
        l_i[e] = l_i[e] * al + ((p0 + p1) + (p2 + p3));  // per-lane partial
        int pr = (quad * 4 + e) * 72 + l16;
        P[pr]      = f2b(p0);
        P[pr + 16] = f2b(p1);
        P[pr + 32] = f2b(p2);
        P[pr + 48] = f2b(p3);
#pragma unroll
        for (int nj = 0; nj < 8; nj++) o_acc[nj][e] *= al;
      }
      bf16x8 pa0 = *(const bf16x8*)(&Ps[wave][l16 * 72 + quad * 8]);
      bf16x8 pa1 = *(const bf16x8*)(&Ps[wave][l16 * 72 + 32 + quad * 8]);
#pragma unroll
      for (int nj = 0; nj < 8; nj++) {
        bf16x8 bv0 = *(const bf16x8*)(&Vs[(nj * 16 + l16) * 72 + quad * 8]);
        bf16x8 bv1 = *(const bf16x8*)(&Vs[(nj * 16 + l16) * 72 + 32 + quad * 8]);
        o_acc[nj] = __builtin_amdgcn_mfma_f32_16x16x32_bf16(pa0, bv0, o_acc[nj], 0, 0, 0);
        o_acc[nj] = __builtin_amdgcn_mfma_f32_16x16x32_bf16(pa1, bv1, o_acc[nj], 0, 0, 0);
      }
    }
  }

  // epilogue: reduce l partials across the 16 column-lanes, then scale+store
  float linv[4];
#pragma unroll
  for (int e = 0; e < 4; e++) {
    float ls = l_i[e];
#pragma unroll
    for (int off = 1; off < 16; off <<= 1)
      ls += __shfl_xor(ls, off, 64);
    linv[e] = 1.0f / ls;
  }
  size_t obase = (((size_t)(b * S_ + qw + quad * 4)) * NH_ + h) * HD_;
#pragma unroll
  for (int nj = 0; nj < 8; nj++) {
#pragma unroll
    for (int e = 0; e < 4; e++) {
      float v = o_acc[nj][e] * linv[e];
      O[obase + (size_t)e * NH_ * HD_ + nj * 16 + l16] = f2b(v);
    }
  }
}

// ---------------- launch ----------------
extern "C" void kernel_launch(void* const* d_in, const int* in_sizes, int n_in,
                              void* d_out, int out_size, void* d_ws, size_t ws_size,
                              hipStream_t stream) {
  const float* x  = (const float*)d_in[0];
  const float* Wq = (const float*)d_in[1];
  const float* Wk = (const float*)d_in[2];
  const float* Wv = (const float*)d_in[3];
  const float* Wo = (const float*)d_in[4];
  const int*  pos = (const int*)d_in[5];
  float* out = (float*)d_out;

  const size_t BS = (size_t)B_ * S_;  // 4096
  const size_t MB = 1024 * 1024;
  char* p = (char*)d_ws;
  u16* xb  = (u16*)(p);             // 32 MB: x bf16; later Wo bf16
  u16* W32 = (u16*)(p + 32 * MB);   // 32 MB: Wq bf16; later attn-out Ob
  u16* W8  = (u16*)(p + 64 * MB);   // 8 MB: Wk, then Wv
  u16* Qb  = (u16*)(p + 72 * MB);   // 32 MB
  u16* Kb  = (u16*)(p + 104 * MB);  // 8 MB
  u16* Vt  = (u16*)(p + 112 * MB);  // 8 MB (V^T, written by gemm epilogue)
  u16* WoB = xb;
  u16* Ob  = W32;

  auto cvt = [&](const float* src, u16* dst, size_t n) {
    int n4 = (int)(n / 4);
    cvt_bf16<<<dim3((n4 + 255) / 256), dim3(256), 0, stream>>>(src, dst, n4);
  };

  cvt(x, xb, BS * H_);
  cvt(Wq, W32, (size_t)H_ * H_);
  gemm_bt<128, 0, u16><<<dim3(H_ / 128, BS / 128), dim3(256), 0, stream>>>(
      xb, W32, Qb, (int)BS, H_, H_);
  cvt(Wk, W8, (size_t)NKV_ * HD_ * H_);
  gemm_bt<128, 0, u16><<<dim3(NKV_ * HD_ / 128, BS / 128), dim3(256), 0, stream>>>(
      xb, W8, Kb, (int)BS, NKV_ * HD_, H_);
  cvt(Wv, W8, (size_t)NKV_ * HD_ * H_);
  gemm_bt<128, 1, u16><<<dim3(NKV_ * HD_ / 128, BS / 128), dim3(256), 0, stream>>>(
      xb, W8, Vt, (int)BS, NKV_ * HD_, H_);

  rope_k<<<dim3((int)(BS * NH_ * 64 / 256)), dim3(256), 0, stream>>>(
      Qb, pos, 5, 0.08838834764831845f);
  rope_k<<<dim3((int)(BS * NKV_ * 64 / 256)), dim3(256), 0, stream>>>(
      Kb, pos, 3, 1.0f);

  attn_k<<<dim3(S_ / 64, NH_, B_), dim3(256), 0, stream>>>(Qb, Kb, Vt, Ob);

  cvt(Wo, WoB, (size_t)H_ * H_);
  gemm_bt<128, 0, float><<<dim3(H_ / 128, BS / 128), dim3(256), 0, stream>>>(
      Ob, WoB, out, (int)BS, H_, H_);
}